// Round 1
// baseline (10576.318 us; speedup 1.0000x reference)
//
#include <hip/hip_runtime.h>
#include <stdint.h>

// LSTM: T=512, B=64, E=1024, H=1024. out[t] = h_{t+1} (fp32).
// Phase A: xw[t*64+b][n] = x @ w_x + bias  (bf16, MFMA GEMM)
// Phase B: persistent kernel, 64 WGs, per-step barrier; each WG owns 16 hidden
//          units (64 gate cols), w_h slice pinned in LDS, c in registers.

#define TSTEPS 512
#define NBATCH 64
#define NHID   1024
#define NGATE  4096
#define NWG2   64

typedef __attribute__((ext_vector_type(8))) short bf16x8;
typedef __attribute__((ext_vector_type(4))) float f32x4;
typedef __attribute__((ext_vector_type(4))) int   i32x4;
typedef __attribute__((ext_vector_type(4))) float fl4;

__device__ __forceinline__ uint16_t f2bf(float f){
  uint32_t u = __float_as_uint(f);
  u += 0x7fffu + ((u >> 16) & 1u);       // round-to-nearest-even
  return (uint16_t)(u >> 16);
}
__device__ __forceinline__ float bf2f(uint16_t b){
  return __uint_as_float(((uint32_t)b) << 16);
}
__device__ __forceinline__ float sigm(float x){ return 1.0f/(1.0f + __expf(-x)); }
__device__ __forceinline__ float tanhfast(float x){ return 1.0f - 2.0f/(__expf(2.0f*x) + 1.0f); }

// ---------------- K0a: fp32 -> bf16 convert (embeds) ----------------
__global__ void k0a_cvt(const float* __restrict__ in, uint16_t* __restrict__ outp, int n8){
  int stride = gridDim.x * blockDim.x;
  for (int i = blockIdx.x * blockDim.x + threadIdx.x; i < n8; i += stride){
    const fl4* p = (const fl4*)(in + (size_t)i * 8);
    fl4 v0 = p[0], v1 = p[1];
    union { uint16_t u[8]; i32x4 v; } r;
    r.u[0]=f2bf(v0.x); r.u[1]=f2bf(v0.y); r.u[2]=f2bf(v0.z); r.u[3]=f2bf(v0.w);
    r.u[4]=f2bf(v1.x); r.u[5]=f2bf(v1.y); r.u[6]=f2bf(v1.z); r.u[7]=f2bf(v1.w);
    *(i32x4*)(outp + (size_t)i * 8) = r.v;
  }
}

// ---------------- K0b: w [2048][4096] f32 -> wT [4096][2048] bf16 ----------------
__global__ void k0b_trans(const float* __restrict__ w, uint16_t* __restrict__ wT){
  __shared__ float tile[64 * 65];
  int k0 = blockIdx.x * 64;       // 0..2047
  int n0 = blockIdx.y * 64;       // 0..4095
  int tid = threadIdx.x;
  int r  = tid >> 2;              // 0..63
  int cq = (tid & 3) * 16;        // 0/16/32/48
#pragma unroll
  for (int i = 0; i < 4; ++i){
    fl4 v = *(const fl4*)(w + (size_t)(k0 + r) * 4096 + n0 + cq + i * 4);
    tile[r*65 + cq + i*4 + 0] = v.x;
    tile[r*65 + cq + i*4 + 1] = v.y;
    tile[r*65 + cq + i*4 + 2] = v.z;
    tile[r*65 + cq + i*4 + 3] = v.w;
  }
  __syncthreads();
  union { uint16_t u[8]; i32x4 v; } a, b;
#pragma unroll
  for (int i = 0; i < 8; ++i) a.u[i] = f2bf(tile[(cq + i) * 65 + r]);
#pragma unroll
  for (int i = 0; i < 8; ++i) b.u[i] = f2bf(tile[(cq + 8 + i) * 65 + r]);
  *(i32x4*)(wT + (size_t)(n0 + r) * 2048 + k0 + cq)     = a.v;
  *(i32x4*)(wT + (size_t)(n0 + r) * 2048 + k0 + cq + 8) = b.v;
}

// ---------------- K1: xw = ebf[32768,1024] @ w_x + bias -> bf16 ----------------
// 128x128 tile, BK=64, 4 waves 2x2, each wave 64x64 (4x4 frags of 16x16x32).
// LDS tiles XOR-swizzled: 16B chunk index ^= (row&7).
__launch_bounds__(256, 2)
__global__ void k1_xw(const uint16_t* __restrict__ ebf, const uint16_t* __restrict__ wT,
                      const float* __restrict__ bias, uint16_t* __restrict__ xw){
  __shared__ char sm[32768];
  char* As = sm;
  char* Bs = sm + 16384;
  int bid = blockIdx.x;
  int nt = bid & 31, mt = bid >> 5;            // consecutive bids share A rows
  int m0 = mt * 128, n0 = nt * 128;
  int tid = threadIdx.x;
  int lane = tid & 63, wid = tid >> 6;
  int wr = wid >> 1, wc = wid & 1;

  f32x4 zero = {0.f, 0.f, 0.f, 0.f};
  f32x4 acc[4][4];
#pragma unroll
  for (int mi = 0; mi < 4; ++mi)
#pragma unroll
    for (int ni = 0; ni < 4; ++ni) acc[mi][ni] = zero;

  for (int kt = 0; kt < 16; ++kt){
    __syncthreads();
#pragma unroll
    for (int i = 0; i < 4; ++i){
      int L = i * 256 + tid;                   // 0..1023
      int row = L >> 3, c = L & 7;
      i32x4 va = *(const i32x4*)(ebf + (size_t)(m0 + row) * 1024 + kt * 64 + c * 8);
      *(i32x4*)(As + row * 128 + ((c ^ (row & 7)) * 16)) = va;
      i32x4 vb = *(const i32x4*)(wT + (size_t)(n0 + row) * 2048 + 1024 + kt * 64 + c * 8);
      *(i32x4*)(Bs + row * 128 + ((c ^ (row & 7)) * 16)) = vb;
    }
    __syncthreads();
#pragma unroll
    for (int kk = 0; kk < 2; ++kk){
      bf16x8 a[4], b[4];
      int ci = kk * 4 + (lane >> 4);
#pragma unroll
      for (int mi = 0; mi < 4; ++mi){
        int rl = wr * 64 + mi * 16 + (lane & 15);
        a[mi] = *(const bf16x8*)(As + rl * 128 + ((ci ^ (rl & 7)) * 16));
      }
#pragma unroll
      for (int ni = 0; ni < 4; ++ni){
        int sl = wc * 64 + ni * 16 + (lane & 15);
        b[ni] = *(const bf16x8*)(Bs + sl * 128 + ((ci ^ (sl & 7)) * 16));
      }
#pragma unroll
      for (int mi = 0; mi < 4; ++mi)
#pragma unroll
        for (int ni = 0; ni < 4; ++ni)
          acc[mi][ni] = __builtin_amdgcn_mfma_f32_16x16x32_bf16(a[mi], b[ni], acc[mi][ni], 0, 0, 0);
    }
  }
  float bcol[4];
#pragma unroll
  for (int ni = 0; ni < 4; ++ni) bcol[ni] = bias[n0 + wc * 64 + ni * 16 + (lane & 15)];
#pragma unroll
  for (int mi = 0; mi < 4; ++mi)
#pragma unroll
    for (int ni = 0; ni < 4; ++ni)
#pragma unroll
      for (int jj = 0; jj < 4; ++jj){
        int rg = m0 + wr * 64 + mi * 16 + (lane >> 4) * 4 + jj;   // D: row=(l>>4)*4+reg
        int cg = n0 + wc * 64 + ni * 16 + (lane & 15);            //    col=l&15
        xw[(size_t)rg * 4096 + cg] = f2bf(acc[mi][ni][jj] + bcol[ni]);
      }
}

// ---------------- K2: persistent recurrent kernel ----------------
// 64 WGs x 256thr. WG wg owns hidden units [wg*16, wg*16+16): gate cols
// n = g*1024 + wg*16 + j. w_h slice (64 rows x 1024 k, bf16, swizzled) pinned in LDS.
// Per step: big[64x64] = h_t @ w_slice, +xw, gates, c in regs, write h fp32+bf16.
// Cross-WG barrier: per-step counter, AGENT-scope release/acquire.
__launch_bounds__(256, 1)
__global__ void k2_rec(const uint16_t* __restrict__ xw, const uint16_t* __restrict__ wT,
                       uint16_t* __restrict__ hbuf, int* __restrict__ cnt,
                       float* __restrict__ outp){
  extern __shared__ char sm[];
  char* WP = sm;                       // 131072: w slice [64][1024] bf16, swizzled
  char* U  = sm + 131072;              // 16640: A double-buffer (2x8192) / big [64][65] f32
  float* big = (float*)U;

  int tid = threadIdx.x;
  int lane = tid & 63, wid = tid >> 6;
  int wr = wid >> 1, wc = wid & 1;
  int wg = blockIdx.x;
  int j0 = wg * 16;

  // pin w_h slice: LDS row s (0..63) <-> n = (s>>4)*1024 + j0 + (s&15)
#pragma unroll
  for (int i = 0; i < 32; ++i){
    int L = i * 256 + tid;             // 0..8191
    int s = L >> 7;                    // 0..63
    int c = L & 127;                   // 16B chunk in 2048B row
    int n = (s >> 4) * 1024 + j0 + (s & 15);
    i32x4 v = *(const i32x4*)(wT + (size_t)n * 2048 + c * 8);
    *(i32x4*)(WP + s * 2048 + ((c ^ (s & 7)) * 16)) = v;
  }
  float creg[4] = {0.f, 0.f, 0.f, 0.f};
  int erow = tid >> 4;                 // epilogue: row = p*16 + erow
  int ej   = tid & 15;                 //           hidden j = j0 + ej
  __syncthreads();

  f32x4 zero = {0.f, 0.f, 0.f, 0.f};

  for (int t = 0; t < TSTEPS; ++t){
    if (t > 0){
      if (tid == 0){
        while (__hip_atomic_load(&cnt[t - 1], __ATOMIC_ACQUIRE, __HIP_MEMORY_SCOPE_AGENT) < NWG2) {}
      }
      __syncthreads();
      __threadfence();                 // acquire: invalidate stale L1/L2
    }
    const uint16_t* hsrc = hbuf + (size_t)t * (NBATCH * NHID);

    // stage A chunk 0
#pragma unroll
    for (int i = 0; i < 2; ++i){
      int L = tid * 2 + i;             // 0..511
      int row = L >> 3, c = L & 7;
      i32x4 v = *(const i32x4*)(hsrc + (size_t)row * 1024 + c * 8);
      *(i32x4*)(U + row * 128 + ((c ^ (row & 7)) * 16)) = v;
    }
    __syncthreads();

    f32x4 acc[2][2];
    acc[0][0] = zero; acc[0][1] = zero; acc[1][0] = zero; acc[1][1] = zero;

    for (int kc = 0; kc < 16; ++kc){
      if (kc < 15){
        char* dst = U + ((kc + 1) & 1) * 8192;
#pragma unroll
        for (int i = 0; i < 2; ++i){
          int L = tid * 2 + i;
          int row = L >> 3, c = L & 7;
          i32x4 v = *(const i32x4*)(hsrc + (size_t)row * 1024 + (kc + 1) * 64 + c * 8);
          *(i32x4*)(dst + row * 128 + ((c ^ (row & 7)) * 16)) = v;
        }
      }
      char* Ab = U + (kc & 1) * 8192;
#pragma unroll
      for (int kk = 0; kk < 2; ++kk){
        bf16x8 a[2], b[2];
        int ci = kk * 4 + (lane >> 4);
#pragma unroll
        for (int mi = 0; mi < 2; ++mi){
          int rl = wr * 32 + mi * 16 + (lane & 15);
          a[mi] = *(const bf16x8*)(Ab + rl * 128 + ((ci ^ (rl & 7)) * 16));
        }
        int ck = kc * 8 + kk * 4 + (lane >> 4);
#pragma unroll
        for (int ni = 0; ni < 2; ++ni){
          int sl = wc * 32 + ni * 16 + (lane & 15);
          b[ni] = *(const bf16x8*)(WP + sl * 2048 + ((ck ^ (sl & 7)) * 16));
        }
#pragma unroll
        for (int mi = 0; mi < 2; ++mi)
#pragma unroll
          for (int ni = 0; ni < 2; ++ni)
            acc[mi][ni] = __builtin_amdgcn_mfma_f32_16x16x32_bf16(a[mi], b[ni], acc[mi][ni], 0, 0, 0);
      }
      __syncthreads();
    }

    // acc -> big (aliases A buffers; safe after final sync above)
#pragma unroll
    for (int mi = 0; mi < 2; ++mi)
#pragma unroll
      for (int ni = 0; ni < 2; ++ni)
#pragma unroll
        for (int jj = 0; jj < 4; ++jj){
          int r  = wr * 32 + mi * 16 + (lane >> 4) * 4 + jj;
          int cc = wc * 32 + ni * 16 + (lane & 15);
          big[r * 65 + cc] = acc[mi][ni][jj];
        }
    __syncthreads();

    // epilogue: gates + state update; big cols: [0:16)=g [16:32)=i [32:48)=f [48:64)=o
    const uint16_t* xwt = xw + (size_t)t * 64 * 4096;
    uint16_t* hdst = hbuf + (size_t)(t + 1) * (NBATCH * NHID);
    float* odst = outp + (size_t)t * (NBATCH * NHID);
#pragma unroll
    for (int p = 0; p < 4; ++p){
      int row = p * 16 + erow;
      float g  = big[row * 65 +  0 + ej] + bf2f(xwt[(size_t)row * 4096 + 0 * 1024 + j0 + ej]);
      float ii = big[row * 65 + 16 + ej] + bf2f(xwt[(size_t)row * 4096 + 1 * 1024 + j0 + ej]);
      float ff = big[row * 65 + 32 + ej] + bf2f(xwt[(size_t)row * 4096 + 2 * 1024 + j0 + ej]);
      float oo = big[row * 65 + 48 + ej] + bf2f(xwt[(size_t)row * 4096 + 3 * 1024 + j0 + ej]);
      g = tanhfast(g); ii = sigm(ii); ff = sigm(ff); oo = sigm(oo);
      float cn = g * ii + creg[p] * ff;
      creg[p] = cn;
      float h = tanhfast(cn) * oo;
      odst[(size_t)row * 1024 + j0 + ej] = h;
      hdst[(size_t)row * 1024 + j0 + ej] = f2bf(h);
    }

    // barrier arrive: all stores drained at syncthreads, then agent-release
    __syncthreads();
    if (tid == 0){
      __threadfence();                 // write-back this XCD's L2
      __hip_atomic_fetch_add(&cnt[t], 1, __ATOMIC_RELEASE, __HIP_MEMORY_SCOPE_AGENT);
    }
  }
}

extern "C" void kernel_launch(void* const* d_in, const int* in_sizes, int n_in,
                              void* d_out, int out_size, void* d_ws, size_t ws_size,
                              hipStream_t stream){
  const float* embeds = (const float*)d_in[0];   // [512,64,1024]
  const float* w      = (const float*)d_in[1];   // [2048,4096]
  const float* bias   = (const float*)d_in[2];   // [4096]
  float* outp = (float*)d_out;
  char* ws = (char*)d_ws;

  const size_t o_ebf = 0;                                   // bf16 [32768][1024]
  const size_t o_wT  = o_ebf + (size_t)32768 * 1024 * 2;    // bf16 [4096][2048]
  const size_t o_xw  = o_wT  + (size_t)4096 * 2048 * 2;     // bf16 [32768][4096]
  const size_t o_hb  = o_xw  + (size_t)32768 * 4096 * 2;    // bf16 [513][64][1024]
  const size_t o_cnt = o_hb  + (size_t)513 * 64 * 1024 * 2; // int [512]

  uint16_t* ebf  = (uint16_t*)(ws + o_ebf);
  uint16_t* wT   = (uint16_t*)(ws + o_wT);
  uint16_t* xw   = (uint16_t*)(ws + o_xw);
  uint16_t* hbuf = (uint16_t*)(ws + o_hb);
  int*      cnt  = (int*)(ws + o_cnt);

  hipMemsetAsync(ws + o_hb, 0, (size_t)64 * 1024 * 2, stream);   // h_0 = 0
  hipMemsetAsync(ws + o_cnt, 0, TSTEPS * sizeof(int), stream);   // barrier counters

  k0a_cvt<<<2048, 256, 0, stream>>>(embeds, ebf, (512 * 64 * 1024) / 8);
  k0b_trans<<<dim3(32, 64), 256, 0, stream>>>(w, wT);
  k1_xw<<<8192, 256, 0, stream>>>(ebf, wT, bias, xw);

  (void)hipFuncSetAttribute((const void*)k2_rec,
                            hipFuncAttributeMaxDynamicSharedMemorySize, 147712);
  k2_rec<<<NWG2, 256, 147712, stream>>>(xw, wT, hbuf, cnt, outp);
}

// Round 2
// 8203.962 us; speedup vs baseline: 1.2892x; 1.2892x over previous
//
#include <hip/hip_runtime.h>
#include <stdint.h>

// LSTM: T=512, B=64, E=1024, H=1024. out[t] = h_{t+1} (fp32).
// Phase A: xw = x @ w_x + bias (bf16 MFMA GEMM, parallel over all T).
// Phase B: persistent kernel, 64 WGs (one per 16 hidden units), per-step
//          global flag sync; w_h slice pinned in LDS; h passed between steps
//          via agent-coherent (sc1/L3) stores; A-operand loaded global->VGPR
//          with a 4-deep pipeline (no syncthreads in K-loop).

#define TSTEPS 512
#define NBATCH 64
#define NHID   1024
#define NWG2   64
#define AGENT  __HIP_MEMORY_SCOPE_AGENT

typedef __attribute__((ext_vector_type(8))) short bf16x8;
typedef __attribute__((ext_vector_type(4))) float f32x4;
typedef __attribute__((ext_vector_type(2))) float f32x2;
typedef __attribute__((ext_vector_type(4))) int   i32x4;
typedef __attribute__((ext_vector_type(4))) float fl4;

__device__ __forceinline__ uint16_t f2bf(float f){
  uint32_t u = __float_as_uint(f);
  u += 0x7fffu + ((u >> 16) & 1u);       // round-to-nearest-even
  return (uint16_t)(u >> 16);
}
__device__ __forceinline__ float bf2f(uint16_t b){
  return __uint_as_float(((uint32_t)b) << 16);
}
__device__ __forceinline__ float sigm(float x){ return 1.0f/(1.0f + __expf(-x)); }
__device__ __forceinline__ float tanhfast(float x){ return 1.0f - 2.0f/(__expf(2.0f*x) + 1.0f); }
__device__ __forceinline__ bf16x8 as_bf(i32x4 v){
  union { i32x4 i; bf16x8 b; } u; u.i = v; return u.b;
}

// ---------------- K0a: fp32 -> bf16 convert (embeds) ----------------
__global__ void k0a_cvt(const float* __restrict__ in, uint16_t* __restrict__ outp, int n8){
  int stride = gridDim.x * blockDim.x;
  for (int i = blockIdx.x * blockDim.x + threadIdx.x; i < n8; i += stride){
    const fl4* p = (const fl4*)(in + (size_t)i * 8);
    fl4 v0 = p[0], v1 = p[1];
    union { uint16_t u[8]; i32x4 v; } r;
    r.u[0]=f2bf(v0.x); r.u[1]=f2bf(v0.y); r.u[2]=f2bf(v0.z); r.u[3]=f2bf(v0.w);
    r.u[4]=f2bf(v1.x); r.u[5]=f2bf(v1.y); r.u[6]=f2bf(v1.z); r.u[7]=f2bf(v1.w);
    *(i32x4*)(outp + (size_t)i * 8) = r.v;
  }
}

// ---------------- K0b: w [2048][4096] f32 -> wT [4096][2048] bf16 ----------------
__global__ void k0b_trans(const float* __restrict__ w, uint16_t* __restrict__ wT){
  __shared__ float tile[64 * 65];
  int k0 = blockIdx.x * 64;
  int n0 = blockIdx.y * 64;
  int tid = threadIdx.x;
  int r  = tid >> 2;
  int cq = (tid & 3) * 16;
#pragma unroll
  for (int i = 0; i < 4; ++i){
    fl4 v = *(const fl4*)(w + (size_t)(k0 + r) * 4096 + n0 + cq + i * 4);
    tile[r*65 + cq + i*4 + 0] = v.x;
    tile[r*65 + cq + i*4 + 1] = v.y;
    tile[r*65 + cq + i*4 + 2] = v.z;
    tile[r*65 + cq + i*4 + 3] = v.w;
  }
  __syncthreads();
  union { uint16_t u[8]; i32x4 v; } a, b;
#pragma unroll
  for (int i = 0; i < 8; ++i) a.u[i] = f2bf(tile[(cq + i) * 65 + r]);
#pragma unroll
  for (int i = 0; i < 8; ++i) b.u[i] = f2bf(tile[(cq + 8 + i) * 65 + r]);
  *(i32x4*)(wT + (size_t)(n0 + r) * 2048 + k0 + cq)     = a.v;
  *(i32x4*)(wT + (size_t)(n0 + r) * 2048 + k0 + cq + 8) = b.v;
}

// ---------------- K1: xw = ebf[32768,1024] @ w_x + bias -> bf16 ----------------
__launch_bounds__(256, 2)
__global__ void k1_xw(const uint16_t* __restrict__ ebf, const uint16_t* __restrict__ wT,
                      const float* __restrict__ bias, uint16_t* __restrict__ xw){
  __shared__ char sm[32768];
  char* As = sm;
  char* Bs = sm + 16384;
  int bid = blockIdx.x;
  int nt = bid & 31, mt = bid >> 5;
  int m0 = mt * 128, n0 = nt * 128;
  int tid = threadIdx.x;
  int lane = tid & 63, wid = tid >> 6;
  int wr = wid >> 1, wc = wid & 1;

  f32x4 zero = {0.f, 0.f, 0.f, 0.f};
  f32x4 acc[4][4];
#pragma unroll
  for (int mi = 0; mi < 4; ++mi)
#pragma unroll
    for (int ni = 0; ni < 4; ++ni) acc[mi][ni] = zero;

  for (int kt = 0; kt < 16; ++kt){
    __syncthreads();
#pragma unroll
    for (int i = 0; i < 4; ++i){
      int L = i * 256 + tid;
      int row = L >> 3, c = L & 7;
      i32x4 va = *(const i32x4*)(ebf + (size_t)(m0 + row) * 1024 + kt * 64 + c * 8);
      *(i32x4*)(As + row * 128 + ((c ^ (row & 7)) * 16)) = va;
      i32x4 vb = *(const i32x4*)(wT + (size_t)(n0 + row) * 2048 + 1024 + kt * 64 + c * 8);
      *(i32x4*)(Bs + row * 128 + ((c ^ (row & 7)) * 16)) = vb;
    }
    __syncthreads();
#pragma unroll
    for (int kk = 0; kk < 2; ++kk){
      bf16x8 a[4], b[4];
      int ci = kk * 4 + (lane >> 4);
#pragma unroll
      for (int mi = 0; mi < 4; ++mi){
        int rl = wr * 64 + mi * 16 + (lane & 15);
        a[mi] = *(const bf16x8*)(As + rl * 128 + ((ci ^ (rl & 7)) * 16));
      }
#pragma unroll
      for (int ni = 0; ni < 4; ++ni){
        int sl = wc * 64 + ni * 16 + (lane & 15);
        b[ni] = *(const bf16x8*)(Bs + sl * 128 + ((ci ^ (sl & 7)) * 16));
      }
#pragma unroll
      for (int mi = 0; mi < 4; ++mi)
#pragma unroll
        for (int ni = 0; ni < 4; ++ni)
          acc[mi][ni] = __builtin_amdgcn_mfma_f32_16x16x32_bf16(a[mi], b[ni], acc[mi][ni], 0, 0, 0);
    }
  }
  float bcol[4];
#pragma unroll
  for (int ni = 0; ni < 4; ++ni) bcol[ni] = bias[n0 + wc * 64 + ni * 16 + (lane & 15)];
#pragma unroll
  for (int mi = 0; mi < 4; ++mi)
#pragma unroll
    for (int ni = 0; ni < 4; ++ni)
#pragma unroll
      for (int jj = 0; jj < 4; ++jj){
        int rg = m0 + wr * 64 + mi * 16 + (lane >> 4) * 4 + jj;
        int cg = n0 + wc * 64 + ni * 16 + (lane & 15);
        xw[(size_t)rg * 4096 + cg] = f2bf(acc[mi][ni][jj] + bcol[ni]);
      }
}

// ---------------- K2: persistent recurrent kernel ----------------
// LDS: WP 131072 (w_h slice [64 gate-cols][1024 K] bf16, chunk-swizzled)
//      XS 9216   (xw tile [64 rows][4 gates][16 j] bf16, 144B/row padded)
//      big 18432 (gate preact [64 rows][72] f32, stride-72 padded)
__launch_bounds__(256, 1)
__global__ void k2_rec(const uint16_t* __restrict__ xw, const uint16_t* __restrict__ wT,
                       uint16_t* __restrict__ hbuf, int* __restrict__ cnt,
                       float* __restrict__ outp){
  extern __shared__ char sm[];
  char*  WP  = sm;
  char*  XS  = sm + 131072;
  float* big = (float*)(sm + 131072 + 9216);

  int tid  = threadIdx.x;
  int lane = tid & 63, wid = tid >> 6;
  int wr = wid >> 1, wc = wid & 1;
  int wg = blockIdx.x;
  int j0 = wg * 16;

  // pin w_h slice: LDS row s (0..63) <-> gate col n = (s>>4)*1024 + j0 + (s&15)
#pragma unroll
  for (int i = 0; i < 32; ++i){
    int L = i * 256 + tid;
    int s = L >> 7;
    int c = L & 127;
    int n = (s >> 4) * 1024 + j0 + (s & 15);
    i32x4 v = *(const i32x4*)(wT + (size_t)n * 2048 + c * 8);
    *(i32x4*)(WP + s * 2048 + ((c ^ (s & 7)) * 16)) = v;
  }

  float creg[4] = {0.f, 0.f, 0.f, 0.f};
  int r8 = tid >> 3;                  // epilogue row (0..31), +32 for item 1
  int jp = tid & 7;                   // epilogue j-pair
  __syncthreads();

  const int slA = wc * 32 + (lane & 15);
  const int slB = slA + 16;
  const int aRow0 = wr * 32 + (lane & 15);
  const int kOff  = (lane >> 4) * 8;

  for (int t = 0; t < TSTEPS; ++t){
    // ---- xw prefetch (step-constant; overlaps the poll) ----
    const uint16_t* xsrc = xw + (size_t)t * 64 * 4096
                              + (size_t)(tid >> 2) * 4096 + (size_t)(tid & 3) * 1024 + j0;
    i32x4 xv0 = *(const i32x4*)(xsrc);
    i32x4 xv1 = *(const i32x4*)(xsrc + 8);

    // ---- wait for h_t ----
    if (t > 0){
      if (tid == 0){
        while (__hip_atomic_load(&cnt[t - 1], __ATOMIC_RELAXED, AGENT) < NWG2) {}
      }
      __syncthreads();
      __builtin_amdgcn_fence(__ATOMIC_ACQUIRE, "agent");   // one L1/L2 inv per step
    }

    // park xw tile in LDS (read after the big-sync below)
    *(i32x4*)(XS + (tid >> 2) * 144 + (tid & 3) * 32)      = xv0;
    *(i32x4*)(XS + (tid >> 2) * 144 + (tid & 3) * 32 + 16) = xv1;

    // ---- GEMM: big = h_t @ w_slice (A direct global->VGPR, 4-deep pipeline) ----
    const uint16_t* hsrc = hbuf + (size_t)t * (NBATCH * NHID);
    const uint16_t* aB0 = hsrc + (size_t)aRow0 * 1024 + kOff;
    const uint16_t* aB1 = aB0 + 16 * 1024;

    i32x4 ap0[4], ap1[4];
#pragma unroll
    for (int i = 0; i < 4; ++i){
      ap0[i] = *(const i32x4*)(aB0 + i * 32);
      ap1[i] = *(const i32x4*)(aB1 + i * 32);
    }
    f32x4 acc00 = {0,0,0,0}, acc01 = {0,0,0,0}, acc10 = {0,0,0,0}, acc11 = {0,0,0,0};
#pragma unroll
    for (int kc = 0; kc < 32; ++kc){
      int ck = kc * 4 + (lane >> 4);
      bf16x8 b0 = *(const bf16x8*)(WP + slA * 2048 + ((ck ^ (slA & 7)) * 16));
      bf16x8 b1 = *(const bf16x8*)(WP + slB * 2048 + ((ck ^ (slB & 7)) * 16));
      bf16x8 a0 = as_bf(ap0[kc & 3]);
      bf16x8 a1 = as_bf(ap1[kc & 3]);
      if (kc < 28){
        ap0[kc & 3] = *(const i32x4*)(aB0 + (kc + 4) * 32);
        ap1[kc & 3] = *(const i32x4*)(aB1 + (kc + 4) * 32);
      }
      acc00 = __builtin_amdgcn_mfma_f32_16x16x32_bf16(a0, b0, acc00, 0, 0, 0);
      acc01 = __builtin_amdgcn_mfma_f32_16x16x32_bf16(a0, b1, acc01, 0, 0, 0);
      acc10 = __builtin_amdgcn_mfma_f32_16x16x32_bf16(a1, b0, acc10, 0, 0, 0);
      acc11 = __builtin_amdgcn_mfma_f32_16x16x32_bf16(a1, b1, acc11, 0, 0, 0);
    }

    // acc -> big   (D: row=(lane>>4)*4+jj, col=lane&15)
    {
      int rbase = wr * 32 + (lane >> 4) * 4;
      int cbase = wc * 32 + (lane & 15);
#pragma unroll
      for (int jj = 0; jj < 4; ++jj){
        big[(rbase      + jj) * 72 + cbase     ] = acc00[jj];
        big[(rbase      + jj) * 72 + cbase + 16] = acc01[jj];
        big[(rbase + 16 + jj) * 72 + cbase     ] = acc10[jj];
        big[(rbase + 16 + jj) * 72 + cbase + 16] = acc11[jj];
      }
    }
    __syncthreads();

    // ---- epilogue: gates, state update, h hand-off ----
    uint16_t* hdst = hbuf + (size_t)(t + 1) * (NBATCH * NHID);
    float*    odst = outp + (size_t)t * (NBATCH * NHID);
#pragma unroll
    for (int it = 0; it < 2; ++it){
      int row = r8 + it * 32;
      const float* bg = big + row * 72 + jp * 2;
      const char*  xr = XS + row * 144 + jp * 4;
      uint32_t xg = *(const uint32_t*)(xr + 0 * 32);
      uint32_t xi = *(const uint32_t*)(xr + 1 * 32);
      uint32_t xf = *(const uint32_t*)(xr + 2 * 32);
      uint32_t xo = *(const uint32_t*)(xr + 3 * 32);
      float G0 = bg[ 0] + bf2f((uint16_t)xg), G1 = bg[ 1] + bf2f((uint16_t)(xg >> 16));
      float I0 = bg[16] + bf2f((uint16_t)xi), I1 = bg[17] + bf2f((uint16_t)(xi >> 16));
      float F0 = bg[32] + bf2f((uint16_t)xf), F1 = bg[33] + bf2f((uint16_t)(xf >> 16));
      float O0 = bg[48] + bf2f((uint16_t)xo), O1 = bg[49] + bf2f((uint16_t)(xo >> 16));
      G0 = tanhfast(G0); G1 = tanhfast(G1);
      I0 = sigm(I0);     I1 = sigm(I1);
      F0 = sigm(F0);     F1 = sigm(F1);
      O0 = sigm(O0);     O1 = sigm(O1);
      float c0 = G0 * I0 + creg[it * 2 + 0] * F0;
      float c1 = G1 * I1 + creg[it * 2 + 1] * F1;
      creg[it * 2 + 0] = c0;
      creg[it * 2 + 1] = c1;
      float h0 = tanhfast(c0) * O0;
      float h1 = tanhfast(c1) * O1;
      size_t idx = (size_t)row * 1024 + j0 + jp * 2;
      *(f32x2*)(odst + idx) = (f32x2){h0, h1};
      uint32_t hp = (uint32_t)f2bf(h0) | ((uint32_t)f2bf(h1) << 16);
      __hip_atomic_store((uint32_t*)(hdst + idx), hp, __ATOMIC_RELAXED, AGENT); // sc1: through to L3
    }

    asm volatile("s_waitcnt vmcnt(0)" ::: "memory");   // h stores at coherent point
    __syncthreads();
    if (tid == 0){
      __hip_atomic_fetch_add(&cnt[t], 1, __ATOMIC_RELAXED, AGENT);
    }
  }
}

extern "C" void kernel_launch(void* const* d_in, const int* in_sizes, int n_in,
                              void* d_out, int out_size, void* d_ws, size_t ws_size,
                              hipStream_t stream){
  const float* embeds = (const float*)d_in[0];   // [512,64,1024]
  const float* w      = (const float*)d_in[1];   // [2048,4096]
  const float* bias   = (const float*)d_in[2];   // [4096]
  float* outp = (float*)d_out;
  char* ws = (char*)d_ws;

  const size_t o_ebf = 0;                                   // bf16 [32768][1024]
  const size_t o_wT  = o_ebf + (size_t)32768 * 1024 * 2;    // bf16 [4096][2048]
  const size_t o_xw  = o_wT  + (size_t)4096 * 2048 * 2;     // bf16 [32768][4096]
  const size_t o_hb  = o_xw  + (size_t)32768 * 4096 * 2;    // bf16 [513][64][1024]
  const size_t o_cnt = o_hb  + (size_t)513 * 64 * 1024 * 2; // int [512]

  uint16_t* ebf  = (uint16_t*)(ws + o_ebf);
  uint16_t* wT   = (uint16_t*)(ws + o_wT);
  uint16_t* xw   = (uint16_t*)(ws + o_xw);
  uint16_t* hbuf = (uint16_t*)(ws + o_hb);
  int*      cnt  = (int*)(ws + o_cnt);

  hipMemsetAsync(ws + o_hb, 0, (size_t)64 * 1024 * 2, stream);   // h_0 = 0
  hipMemsetAsync(ws + o_cnt, 0, TSTEPS * sizeof(int), stream);   // flags = 0 every replay

  k0a_cvt<<<2048, 256, 0, stream>>>(embeds, ebf, (512 * 64 * 1024) / 8);
  k0b_trans<<<dim3(32, 64), 256, 0, stream>>>(w, wT);
  k1_xw<<<8192, 256, 0, stream>>>(ebf, wT, bias, xw);

  (void)hipFuncSetAttribute((const void*)k2_rec,
                            hipFuncAttributeMaxDynamicSharedMemorySize, 158720);
  k2_rec<<<NWG2, 256, 158720, stream>>>(xw, wT, hbuf, cnt, outp);
}

// Round 4
// 5301.311 us; speedup vs baseline: 1.9950x; 1.5475x over previous
//
#include <hip/hip_runtime.h>
#include <stdint.h>

// LSTM: T=512, B=64, E=1024, H=1024. out[t] = h_{t+1} (fp32).
// Phase A: xw = x @ w_x + bias (bf16 MFMA GEMM, parallel over all T).
// Phase B: persistent kernel, 64 WGs (16 hidden units each), w_h slice pinned
//          in LDS. Per wave: 16 batch rows x all 64 gate cols -> in-register
//          epilogue (no LDS round-trip). A (h_t) loaded global->VGPR, ALL 32
//          16B-loads issued up-front. Cross-WG sync: per-WG flag array padded
//          to one cache line each (no false sharing), s_sleep backoff in poll,
//          one agent-acquire fence per step.

#define TSTEPS 512
#define NBATCH 64
#define NHID   1024
#define NWG2   64
#define FLAGSTRIDE 32        // ints; 128B between flags
#define AGENT  __HIP_MEMORY_SCOPE_AGENT

typedef __attribute__((ext_vector_type(8))) short bf16x8;
typedef __attribute__((ext_vector_type(4))) float f32x4;
typedef __attribute__((ext_vector_type(4))) int   i32x4;
typedef __attribute__((ext_vector_type(4))) float fl4;

__device__ __forceinline__ uint16_t f2bf(float f){
  uint32_t u = __float_as_uint(f);
  u += 0x7fffu + ((u >> 16) & 1u);       // round-to-nearest-even
  return (uint16_t)(u >> 16);
}
__device__ __forceinline__ float bf2f(uint16_t b){
  return __uint_as_float(((uint32_t)b) << 16);
}
__device__ __forceinline__ float sigm(float x){ return 1.0f/(1.0f + __expf(-x)); }
__device__ __forceinline__ float tanhfast(float x){ return 1.0f - 2.0f/(__expf(2.0f*x) + 1.0f); }
__device__ __forceinline__ bf16x8 as_bf(i32x4 v){
  union { i32x4 i; bf16x8 b; } u; u.i = v; return u.b;
}

// ---------------- K0a: fp32 -> bf16 convert (embeds) ----------------
__global__ void k0a_cvt(const float* __restrict__ in, uint16_t* __restrict__ outp, int n8){
  int stride = gridDim.x * blockDim.x;
  for (int i = blockIdx.x * blockDim.x + threadIdx.x; i < n8; i += stride){
    const fl4* p = (const fl4*)(in + (size_t)i * 8);
    fl4 v0 = p[0], v1 = p[1];
    union { uint16_t u[8]; i32x4 v; } r;
    r.u[0]=f2bf(v0.x); r.u[1]=f2bf(v0.y); r.u[2]=f2bf(v0.z); r.u[3]=f2bf(v0.w);
    r.u[4]=f2bf(v1.x); r.u[5]=f2bf(v1.y); r.u[6]=f2bf(v1.z); r.u[7]=f2bf(v1.w);
    *(i32x4*)(outp + (size_t)i * 8) = r.v;
  }
}

// ---------------- K0b: w [2048][4096] f32 -> wT [4096][2048] bf16 ----------------
__global__ void k0b_trans(const float* __restrict__ w, uint16_t* __restrict__ wT){
  __shared__ float tile[64 * 65];
  int k0 = blockIdx.x * 64;
  int n0 = blockIdx.y * 64;
  int tid = threadIdx.x;
  int r  = tid >> 2;
  int cq = (tid & 3) * 16;
#pragma unroll
  for (int i = 0; i < 4; ++i){
    fl4 v = *(const fl4*)(w + (size_t)(k0 + r) * 4096 + n0 + cq + i * 4);
    tile[r*65 + cq + i*4 + 0] = v.x;
    tile[r*65 + cq + i*4 + 1] = v.y;
    tile[r*65 + cq + i*4 + 2] = v.z;
    tile[r*65 + cq + i*4 + 3] = v.w;
  }
  __syncthreads();
  union { uint16_t u[8]; i32x4 v; } a, b;
#pragma unroll
  for (int i = 0; i < 8; ++i) a.u[i] = f2bf(tile[(cq + i) * 65 + r]);
#pragma unroll
  for (int i = 0; i < 8; ++i) b.u[i] = f2bf(tile[(cq + 8 + i) * 65 + r]);
  *(i32x4*)(wT + (size_t)(n0 + r) * 2048 + k0 + cq)     = a.v;
  *(i32x4*)(wT + (size_t)(n0 + r) * 2048 + k0 + cq + 8) = b.v;
}

// ---------------- K1: xw = ebf[32768,1024] @ w_x + bias -> bf16 ----------------
__launch_bounds__(256, 2)
__global__ void k1_xw(const uint16_t* __restrict__ ebf, const uint16_t* __restrict__ wT,
                      const float* __restrict__ bias, uint16_t* __restrict__ xw){
  __shared__ char sm[32768];
  char* As = sm;
  char* Bs = sm + 16384;
  int bid = blockIdx.x;
  int nt = bid & 31, mt = bid >> 5;
  int m0 = mt * 128, n0 = nt * 128;
  int tid = threadIdx.x;
  int lane = tid & 63, wid = tid >> 6;
  int wr = wid >> 1, wc = wid & 1;

  f32x4 zero = {0.f, 0.f, 0.f, 0.f};
  f32x4 acc[4][4];
#pragma unroll
  for (int mi = 0; mi < 4; ++mi)
#pragma unroll
    for (int ni = 0; ni < 4; ++ni) acc[mi][ni] = zero;

  for (int kt = 0; kt < 16; ++kt){
    __syncthreads();
#pragma unroll
    for (int i = 0; i < 4; ++i){
      int L = i * 256 + tid;
      int row = L >> 3, c = L & 7;
      i32x4 va = *(const i32x4*)(ebf + (size_t)(m0 + row) * 1024 + kt * 64 + c * 8);
      *(i32x4*)(As + row * 128 + ((c ^ (row & 7)) * 16)) = va;
      i32x4 vb = *(const i32x4*)(wT + (size_t)(n0 + row) * 2048 + 1024 + kt * 64 + c * 8);
      *(i32x4*)(Bs + row * 128 + ((c ^ (row & 7)) * 16)) = vb;
    }
    __syncthreads();
#pragma unroll
    for (int kk = 0; kk < 2; ++kk){
      bf16x8 a[4], b[4];
      int ci = kk * 4 + (lane >> 4);
#pragma unroll
      for (int mi = 0; mi < 4; ++mi){
        int rl = wr * 64 + mi * 16 + (lane & 15);
        a[mi] = *(const bf16x8*)(As + rl * 128 + ((ci ^ (rl & 7)) * 16));
      }
#pragma unroll
      for (int ni = 0; ni < 4; ++ni){
        int sl = wc * 64 + ni * 16 + (lane & 15);
        b[ni] = *(const bf16x8*)(Bs + sl * 128 + ((ci ^ (sl & 7)) * 16));
      }
#pragma unroll
      for (int mi = 0; mi < 4; ++mi)
#pragma unroll
        for (int ni = 0; ni < 4; ++ni)
          acc[mi][ni] = __builtin_amdgcn_mfma_f32_16x16x32_bf16(a[mi], b[ni], acc[mi][ni], 0, 0, 0);
    }
  }
  float bcol[4];
#pragma unroll
  for (int ni = 0; ni < 4; ++ni) bcol[ni] = bias[n0 + wc * 64 + ni * 16 + (lane & 15)];
#pragma unroll
  for (int mi = 0; mi < 4; ++mi)
#pragma unroll
    for (int ni = 0; ni < 4; ++ni)
#pragma unroll
      for (int jj = 0; jj < 4; ++jj){
        int rg = m0 + wr * 64 + mi * 16 + (lane >> 4) * 4 + jj;
        int cg = n0 + wc * 64 + ni * 16 + (lane & 15);
        xw[(size_t)rg * 4096 + cg] = f2bf(acc[mi][ni][jj] + bcol[ni]);
      }
}

// ---------------- K2: persistent recurrent kernel ----------------
// LDS: WP 131072 only (w_h slice [64 gate-cols][1024 K] bf16, chunk-swizzled).
// Wave wid: batch rows [wid*16, wid*16+16), all 64 gate cols.
// Thread (wid, q=lane>>4, rr=lane&15): rows wid*16+q*4+{0..3}, hidden j0+rr,
// all 4 gates in acc[g] -> gate math entirely in registers.
__launch_bounds__(256, 1)
__global__ void k2_rec(const uint16_t* __restrict__ xw, const uint16_t* __restrict__ wT,
                       uint16_t* __restrict__ hbuf, int* __restrict__ flags,
                       float* __restrict__ outp){
  extern __shared__ char sm[];
  char* WP = sm;                       // 131072: [64 rows][1024 k] bf16, swizzled

  int tid  = threadIdx.x;
  int lane = tid & 63, wid = tid >> 6;
  int wg = blockIdx.x;
  int j0 = wg * 16;

  // pin w_h slice: LDS row s (0..63) <-> gate col n = (s>>4)*1024 + j0 + (s&15)
#pragma unroll
  for (int i = 0; i < 32; ++i){
    int L = i * 256 + tid;
    int s = L >> 7;
    int c = L & 127;
    int n = (s >> 4) * 1024 + j0 + (s & 15);
    i32x4 v = *(const i32x4*)(wT + (size_t)n * 2048 + c * 8);
    *(i32x4*)(WP + s * 2048 + ((c ^ (s & 7)) * 16)) = v;
  }
  __syncthreads();

  const int r0 = wid * 16;             // wave's batch-row block
  const int q  = lane >> 4;            // k-chunk phase / row sub-block
  const int rr = lane & 15;            // hidden-unit index (and B col)

  float creg[4] = {0.f, 0.f, 0.f, 0.f};

  for (int t = 0; t < TSTEPS; ++t){
    // ---- xw prefetch: 16 scalars per thread (step-known; hides under poll) ----
    const uint16_t* xwt = xw + (size_t)t * (64 * 4096) + j0 + rr;
    uint16_t xwr[4][4];
#pragma unroll
    for (int g = 0; g < 4; ++g)
#pragma unroll
      for (int p = 0; p < 4; ++p)
        xwr[g][p] = xwt[(size_t)(r0 + q * 4 + p) * 4096 + g * 1024];

    // ---- wait for h_t: wave 0 polls 64 line-padded flags; s_sleep backoff ----
    if (t > 0){
      if (tid < 64){
        while (true){
          int v = __hip_atomic_load(&flags[tid * FLAGSTRIDE], __ATOMIC_RELAXED, AGENT);
          if (__all(v >= t)) break;
          __builtin_amdgcn_s_sleep(1);
        }
      }
      __syncthreads();
      __builtin_amdgcn_fence(__ATOMIC_ACQUIRE, "agent");   // one inv per step
    }

    // ---- A: issue ALL 32 16B h-loads up-front (128 VGPR in flight) ----
    const uint16_t* hsrc = hbuf + (size_t)t * (NBATCH * NHID);
    const uint16_t* aB = hsrc + (size_t)(r0 + rr) * 1024 + q * 8;
    i32x4 ap[32];
#pragma unroll
    for (int kc = 0; kc < 32; ++kc)
      ap[kc] = *(const i32x4*)(aB + kc * 32);
    __builtin_amdgcn_sched_barrier(0);   // keep the load cluster ahead of the loop

    // ---- GEMM: acc[g] = h_rows @ w[:, gate g cols], B 4-deep LDS pipeline ----
    f32x4 acc[4];
#pragma unroll
    for (int g = 0; g < 4; ++g) acc[g] = (f32x4){0.f, 0.f, 0.f, 0.f};

    bf16x8 b[4][4];                      // [pipeline slot][gate]
#pragma unroll
    for (int kc = 0; kc < 3; ++kc)
#pragma unroll
      for (int g = 0; g < 4; ++g){
        int s = g * 16 + rr;
        int ck = kc * 4 + q;
        b[kc][g] = *(const bf16x8*)(WP + s * 2048 + ((ck ^ (s & 7)) * 16));
      }

#pragma unroll
    for (int kc = 0; kc < 32; ++kc){
      if (kc < 29){
#pragma unroll
        for (int g = 0; g < 4; ++g){
          int s = g * 16 + rr;
          int ck = (kc + 3) * 4 + q;
          b[(kc + 3) & 3][g] = *(const bf16x8*)(WP + s * 2048 + ((ck ^ (s & 7)) * 16));
        }
      }
      bf16x8 a = as_bf(ap[kc]);
#pragma unroll
      for (int g = 0; g < 4; ++g)
        acc[g] = __builtin_amdgcn_mfma_f32_16x16x32_bf16(a, b[kc & 3][g], acc[g], 0, 0, 0);
    }

    // ---- epilogue: fully in-register gate math; h hand-off via agent stores ----
    uint16_t* hdst = hbuf + (size_t)(t + 1) * (NBATCH * NHID);
    float*    odst = outp + (size_t)t * (NBATCH * NHID);
#pragma unroll
    for (int p = 0; p < 4; ++p){
      int row = r0 + q * 4 + p;          // D: row = (lane>>4)*4 + reg
      float G = acc[0][p] + bf2f(xwr[0][p]);
      float I = acc[1][p] + bf2f(xwr[1][p]);
      float F = acc[2][p] + bf2f(xwr[2][p]);
      float O = acc[3][p] + bf2f(xwr[3][p]);
      G = tanhfast(G); I = sigm(I); F = sigm(F); O = sigm(O);
      float c = G * I + creg[p] * F;
      creg[p] = c;
      float h = tanhfast(c) * O;
      size_t idx = (size_t)row * 1024 + j0 + rr;
      odst[idx] = h;
      __hip_atomic_store(hdst + idx, f2bf(h), __ATOMIC_RELAXED, AGENT); // through to L3
    }

    asm volatile("s_waitcnt vmcnt(0)" ::: "memory");   // h stores at coherent point
    __syncthreads();
    if (tid == 0)
      __hip_atomic_store(&flags[wg * FLAGSTRIDE], t + 1, __ATOMIC_RELAXED, AGENT);
  }
}

extern "C" void kernel_launch(void* const* d_in, const int* in_sizes, int n_in,
                              void* d_out, int out_size, void* d_ws, size_t ws_size,
                              hipStream_t stream){
  const float* embeds = (const float*)d_in[0];   // [512,64,1024]
  const float* w      = (const float*)d_in[1];   // [2048,4096]
  const float* bias   = (const float*)d_in[2];   // [4096]
  float* outp = (float*)d_out;
  char* ws = (char*)d_ws;

  const size_t o_ebf = 0;                                   // bf16 [32768][1024]
  const size_t o_wT  = o_ebf + (size_t)32768 * 1024 * 2;    // bf16 [4096][2048]
  const size_t o_xw  = o_wT  + (size_t)4096 * 2048 * 2;     // bf16 [32768][4096]
  const size_t o_hb  = o_xw  + (size_t)32768 * 4096 * 2;    // bf16 [513][64][1024]
  const size_t o_fl  = o_hb  + (size_t)513 * 64 * 1024 * 2; // int [64*32] line-padded

  uint16_t* ebf  = (uint16_t*)(ws + o_ebf);
  uint16_t* wT   = (uint16_t*)(ws + o_wT);
  uint16_t* xw   = (uint16_t*)(ws + o_xw);
  uint16_t* hbuf = (uint16_t*)(ws + o_hb);
  int*      flags= (int*)(ws + o_fl);

  hipMemsetAsync(ws + o_hb, 0, (size_t)64 * 1024 * 2, stream);          // h_0 = 0
  hipMemsetAsync(ws + o_fl, 0, NWG2 * FLAGSTRIDE * sizeof(int), stream); // flags = 0 every replay

  k0a_cvt<<<2048, 256, 0, stream>>>(embeds, ebf, (512 * 64 * 1024) / 8);
  k0b_trans<<<dim3(32, 64), 256, 0, stream>>>(w, wT);
  k1_xw<<<8192, 256, 0, stream>>>(ebf, wT, bias, xw);

  (void)hipFuncSetAttribute((const void*)k2_rec,
                            hipFuncAttributeMaxDynamicSharedMemorySize, 131072);
  k2_rec<<<NWG2, 256, 131072, stream>>>(xw, wT, hbuf, flags, outp);
}

// Round 5
// 4559.723 us; speedup vs baseline: 2.3195x; 1.1626x over previous
//
#include <hip/hip_runtime.h>
#include <stdint.h>

// LSTM: T=512, B=64, E=1024, H=1024. out[t] = h_{t+1} (fp32).
// Phase A: xw = x @ w_x + bias (bf16 MFMA GEMM, parallel over all T).
// Phase B: persistent kernel, 64 WGs (16 hidden units each), w_h slice pinned
//          in LDS in per-(kc,gate) fragment layout (conflict-free ds_read_b128).
//          A (h_t) loaded via inline-asm global_load_dwordx4 sc0 sc1 (coherent
//          from L3 -> NO acquire fence), consumed in 4 blocks with counted
//          vmcnt waits. xw prefetched one step ahead into registers. Cross-WG
//          sync: line-padded per-WG flags, s_sleep backoff poll.

#define TSTEPS 512
#define NBATCH 64
#define NHID   1024
#define NWG2   64
#define FLAGSTRIDE 32        // ints; 128B between flags
#define AGENT  __HIP_MEMORY_SCOPE_AGENT

typedef __attribute__((ext_vector_type(8))) short bf16x8;
typedef __attribute__((ext_vector_type(4))) float f32x4;
typedef __attribute__((ext_vector_type(4))) int   i32x4;
typedef __attribute__((ext_vector_type(4))) float fl4;

__device__ __forceinline__ uint16_t f2bf(float f){
  uint32_t u = __float_as_uint(f);
  u += 0x7fffu + ((u >> 16) & 1u);       // round-to-nearest-even
  return (uint16_t)(u >> 16);
}
__device__ __forceinline__ float bf2f(uint16_t b){
  return __uint_as_float(((uint32_t)b) << 16);
}
__device__ __forceinline__ float sigm(float x){ return 1.0f/(1.0f + __expf(-x)); }
__device__ __forceinline__ float tanhfast(float x){ return 1.0f - 2.0f/(__expf(2.0f*x) + 1.0f); }
__device__ __forceinline__ bf16x8 as_bf(i32x4 v){
  union { i32x4 i; bf16x8 b; } u; u.i = v; return u.b;
}

// ---------------- K0a: fp32 -> bf16 convert (embeds) ----------------
__global__ void k0a_cvt(const float* __restrict__ in, uint16_t* __restrict__ outp, int n8){
  int stride = gridDim.x * blockDim.x;
  for (int i = blockIdx.x * blockDim.x + threadIdx.x; i < n8; i += stride){
    const fl4* p = (const fl4*)(in + (size_t)i * 8);
    fl4 v0 = p[0], v1 = p[1];
    union { uint16_t u[8]; i32x4 v; } r;
    r.u[0]=f2bf(v0.x); r.u[1]=f2bf(v0.y); r.u[2]=f2bf(v0.z); r.u[3]=f2bf(v0.w);
    r.u[4]=f2bf(v1.x); r.u[5]=f2bf(v1.y); r.u[6]=f2bf(v1.z); r.u[7]=f2bf(v1.w);
    *(i32x4*)(outp + (size_t)i * 8) = r.v;
  }
}

// ---------------- K0b: w [2048][4096] f32 -> wT [4096][2048] bf16 ----------------
__global__ void k0b_trans(const float* __restrict__ w, uint16_t* __restrict__ wT){
  __shared__ float tile[64 * 65];
  int k0 = blockIdx.x * 64;
  int n0 = blockIdx.y * 64;
  int tid = threadIdx.x;
  int r  = tid >> 2;
  int cq = (tid & 3) * 16;
#pragma unroll
  for (int i = 0; i < 4; ++i){
    fl4 v = *(const fl4*)(w + (size_t)(k0 + r) * 4096 + n0 + cq + i * 4);
    tile[r*65 + cq + i*4 + 0] = v.x;
    tile[r*65 + cq + i*4 + 1] = v.y;
    tile[r*65 + cq + i*4 + 2] = v.z;
    tile[r*65 + cq + i*4 + 3] = v.w;
  }
  __syncthreads();
  union { uint16_t u[8]; i32x4 v; } a, b;
#pragma unroll
  for (int i = 0; i < 8; ++i) a.u[i] = f2bf(tile[(cq + i) * 65 + r]);
#pragma unroll
  for (int i = 0; i < 8; ++i) b.u[i] = f2bf(tile[(cq + 8 + i) * 65 + r]);
  *(i32x4*)(wT + (size_t)(n0 + r) * 2048 + k0 + cq)     = a.v;
  *(i32x4*)(wT + (size_t)(n0 + r) * 2048 + k0 + cq + 8) = b.v;
}

// ---------------- K1: xw = ebf[32768,1024] @ w_x + bias -> bf16 ----------------
__launch_bounds__(256, 2)
__global__ void k1_xw(const uint16_t* __restrict__ ebf, const uint16_t* __restrict__ wT,
                      const float* __restrict__ bias, uint16_t* __restrict__ xw){
  __shared__ char sm[32768];
  char* As = sm;
  char* Bs = sm + 16384;
  int bid = blockIdx.x;
  int nt = bid & 31, mt = bid >> 5;
  int m0 = mt * 128, n0 = nt * 128;
  int tid = threadIdx.x;
  int lane = tid & 63, wid = tid >> 6;
  int wr = wid >> 1, wc = wid & 1;

  f32x4 zero = {0.f, 0.f, 0.f, 0.f};
  f32x4 acc[4][4];
#pragma unroll
  for (int mi = 0; mi < 4; ++mi)
#pragma unroll
    for (int ni = 0; ni < 4; ++ni) acc[mi][ni] = zero;

  for (int kt = 0; kt < 16; ++kt){
    __syncthreads();
#pragma unroll
    for (int i = 0; i < 4; ++i){
      int L = i * 256 + tid;
      int row = L >> 3, c = L & 7;
      i32x4 va = *(const i32x4*)(ebf + (size_t)(m0 + row) * 1024 + kt * 64 + c * 8);
      *(i32x4*)(As + row * 128 + ((c ^ (row & 7)) * 16)) = va;
      i32x4 vb = *(const i32x4*)(wT + (size_t)(n0 + row) * 2048 + 1024 + kt * 64 + c * 8);
      *(i32x4*)(Bs + row * 128 + ((c ^ (row & 7)) * 16)) = vb;
    }
    __syncthreads();
#pragma unroll
    for (int kk = 0; kk < 2; ++kk){
      bf16x8 a[4], b[4];
      int ci = kk * 4 + (lane >> 4);
#pragma unroll
      for (int mi = 0; mi < 4; ++mi){
        int rl = wr * 64 + mi * 16 + (lane & 15);
        a[mi] = *(const bf16x8*)(As + rl * 128 + ((ci ^ (rl & 7)) * 16));
      }
#pragma unroll
      for (int ni = 0; ni < 4; ++ni){
        int sl = wc * 64 + ni * 16 + (lane & 15);
        b[ni] = *(const bf16x8*)(Bs + sl * 128 + ((ci ^ (sl & 7)) * 16));
      }
#pragma unroll
      for (int mi = 0; mi < 4; ++mi)
#pragma unroll
        for (int ni = 0; ni < 4; ++ni)
          acc[mi][ni] = __builtin_amdgcn_mfma_f32_16x16x32_bf16(a[mi], b[ni], acc[mi][ni], 0, 0, 0);
    }
  }
  float bcol[4];
#pragma unroll
  for (int ni = 0; ni < 4; ++ni) bcol[ni] = bias[n0 + wc * 64 + ni * 16 + (lane & 15)];
#pragma unroll
  for (int mi = 0; mi < 4; ++mi)
#pragma unroll
    for (int ni = 0; ni < 4; ++ni)
#pragma unroll
      for (int jj = 0; jj < 4; ++jj){
        int rg = m0 + wr * 64 + mi * 16 + (lane >> 4) * 4 + jj;
        int cg = n0 + wc * 64 + ni * 16 + (lane & 15);
        xw[(size_t)rg * 4096 + cg] = f2bf(acc[mi][ni][jj] + bcol[ni]);
      }
}

// ---------------- K2: persistent recurrent kernel ----------------
// WP layout (131072B): fragment-major. Fragment (kc,g,lane) at
// WP + ((kc*4+g)*64 + lane)*16, holding w_h[k=kc*32+q*8..+8][col=g*1024+j0+rr]
// where q=lane>>4, rr=lane&15. ds_read_b128 is lane-sequential -> conflict-free.
#define LDA(k, OFF) asm volatile("global_load_dwordx4 %0, %1, off offset:" #OFF " sc0 sc1" \
                                 : "=v"(ap[k]) : "v"(aB) : "memory")
#define WAITV(N) do { asm volatile("s_waitcnt vmcnt(" #N ")" ::: "memory"); \
                      __builtin_amdgcn_sched_barrier(0); } while(0)
#define GBLK(K0) \
  _Pragma("unroll") \
  for (int kc = K0; kc < K0 + 8; ++kc){ \
    bf16x8 a = as_bf(ap[kc]); \
    _Pragma("unroll") \
    for (int g = 0; g < 4; ++g){ \
      bf16x8 b = *(const bf16x8*)(WP + ((kc * 4 + g) << 10) + (lane << 4)); \
      acc[g] = __builtin_amdgcn_mfma_f32_16x16x32_bf16(a, b, acc[g], 0, 0, 0); \
    } \
  }

__launch_bounds__(256, 1)
__global__ void k2_rec(const uint16_t* __restrict__ xw, const uint16_t* __restrict__ wT,
                       uint16_t* __restrict__ hbuf, int* __restrict__ flags,
                       float* __restrict__ outp){
  extern __shared__ char sm[];
  char* WP = sm;                       // 131072

  int tid  = threadIdx.x;
  int lane = tid & 63;
  int wid  = tid >> 6;
  int wg = blockIdx.x;
  int j0 = wg * 16;

  // pin w_h slice in fragment-major layout
#pragma unroll
  for (int i = 0; i < 32; ++i){
    int L = i * 256 + tid;             // fragment id 0..8191
    int kc = L >> 8;
    int g  = (L >> 6) & 3;
    int l6 = L & 63;
    int q  = (l6 >> 4) & 3;
    int rr = l6 & 15;
    i32x4 v = *(const i32x4*)(wT + (size_t)(g * 1024 + j0 + rr) * 2048 + kc * 32 + q * 8);
    *(i32x4*)(WP + (size_t)L * 16) = v;
  }
  __syncthreads();

  const int r0 = wid * 16;             // wave's batch-row block
  const int q  = lane >> 4;            // k-phase / D-row sub-block
  const int rr = lane & 15;            // hidden-unit index

  float creg[4] = {0.f, 0.f, 0.f, 0.f};

  // xw for t=0 preloaded into registers
  uint16_t xc[4][4];
  {
    const uint16_t* xp = xw + (size_t)0 * (64 * 4096) + j0 + rr;
#pragma unroll
    for (int g = 0; g < 4; ++g)
#pragma unroll
      for (int p = 0; p < 4; ++p)
        xc[g][p] = xp[(size_t)(r0 + q * 4 + p) * 4096 + g * 1024];
  }

  for (int t = 0; t < TSTEPS; ++t){
    // ---- wait for h_t (zero outstanding vmem here -> clean poll) ----
    if (t > 0){
      if (tid < 64){
        while (true){
          int v = __hip_atomic_load(&flags[tid * FLAGSTRIDE], __ATOMIC_RELAXED, AGENT);
          if (__all(v >= t)) break;
          __builtin_amdgcn_s_sleep(1);
        }
      }
      __syncthreads();
      // no fence: A-loads below are sc0 sc1 (coherent read from L3)
    }

    // ---- A: 32 coherent 16B loads, all issued, all VGPRs held live ----
    const uint16_t* hsrc = hbuf + (size_t)t * (NBATCH * NHID);
    const uint16_t* aB = hsrc + (size_t)(r0 + rr) * 1024 + q * 8;
    i32x4 ap[32];
    LDA(0,0);     LDA(1,64);    LDA(2,128);   LDA(3,192);
    LDA(4,256);   LDA(5,320);   LDA(6,384);   LDA(7,448);
    LDA(8,512);   LDA(9,576);   LDA(10,640);  LDA(11,704);
    LDA(12,768);  LDA(13,832);  LDA(14,896);  LDA(15,960);
    LDA(16,1024); LDA(17,1088); LDA(18,1152); LDA(19,1216);
    LDA(20,1280); LDA(21,1344); LDA(22,1408); LDA(23,1472);
    LDA(24,1536); LDA(25,1600); LDA(26,1664); LDA(27,1728);
    LDA(28,1792); LDA(29,1856); LDA(30,1920); LDA(31,1984);

    // ---- xw prefetch for t+1 (younger than A-loads; never gates the waits) ----
    uint16_t xn[4][4];
    {
      int tn = (t < TSTEPS - 1) ? t + 1 : t;   // unconditional: keeps vmcnt counts fixed
      const uint16_t* xp = xw + (size_t)tn * (64 * 4096) + j0 + rr;
#pragma unroll
      for (int g = 0; g < 4; ++g)
#pragma unroll
        for (int p = 0; p < 4; ++p)
          xn[g][p] = xp[(size_t)(r0 + q * 4 + p) * 4096 + g * 1024];
    }

    // ---- GEMM: 4 blocks of 8 kc, counted vmcnt (16 xw stay in flight) ----
    f32x4 acc[4];
#pragma unroll
    for (int g = 0; g < 4; ++g) acc[g] = (f32x4){0.f, 0.f, 0.f, 0.f};

    WAITV(40); GBLK(0);
    WAITV(32); GBLK(8);
    WAITV(24); GBLK(16);
    WAITV(16); GBLK(24);

    // ---- epilogue: in-register gate math; h hand-off via agent stores ----
    uint16_t* hdst = hbuf + (size_t)(t + 1) * (NBATCH * NHID);
    float*    odst = outp + (size_t)t * (NBATCH * NHID);
#pragma unroll
    for (int p = 0; p < 4; ++p){
      int row = r0 + q * 4 + p;          // D: row = (lane>>4)*4 + reg
      float G = acc[0][p] + bf2f(xc[0][p]);
      float I = acc[1][p] + bf2f(xc[1][p]);
      float F = acc[2][p] + bf2f(xc[2][p]);
      float O = acc[3][p] + bf2f(xc[3][p]);
      G = tanhfast(G); I = sigm(I); F = sigm(F); O = sigm(O);
      float c = G * I + creg[p] * F;
      creg[p] = c;
      float h = tanhfast(c) * O;
      size_t idx = (size_t)row * 1024 + j0 + rr;
      odst[idx] = h;
      __hip_atomic_store(hdst + idx, f2bf(h), __ATOMIC_RELAXED, AGENT); // through to L3
    }

    // rotate xw regs
#pragma unroll
    for (int g = 0; g < 4; ++g)
#pragma unroll
      for (int p = 0; p < 4; ++p)
        xc[g][p] = xn[g][p];

    asm volatile("s_waitcnt vmcnt(0)" ::: "memory");   // h stores at coherent point
    __syncthreads();
    if (tid == 0)
      __hip_atomic_store(&flags[wg * FLAGSTRIDE], t + 1, __ATOMIC_RELAXED, AGENT);
  }
}

extern "C" void kernel_launch(void* const* d_in, const int* in_sizes, int n_in,
                              void* d_out, int out_size, void* d_ws, size_t ws_size,
                              hipStream_t stream){
  const float* embeds = (const float*)d_in[0];   // [512,64,1024]
  const float* w      = (const float*)d_in[1];   // [2048,4096]
  const float* bias   = (const float*)d_in[2];   // [4096]
  float* outp = (float*)d_out;
  char* ws = (char*)d_ws;

  const size_t o_ebf = 0;                                   // bf16 [32768][1024]
  const size_t o_wT  = o_ebf + (size_t)32768 * 1024 * 2;    // bf16 [4096][2048]
  const size_t o_xw  = o_wT  + (size_t)4096 * 2048 * 2;     // bf16 [32768][4096]
  const size_t o_hb  = o_xw  + (size_t)32768 * 4096 * 2;    // bf16 [513][64][1024]
  const size_t o_fl  = o_hb  + (size_t)513 * 64 * 1024 * 2; // int [64*32] line-padded

  uint16_t* ebf  = (uint16_t*)(ws + o_ebf);
  uint16_t* wT   = (uint16_t*)(ws + o_wT);
  uint16_t* xw   = (uint16_t*)(ws + o_xw);
  uint16_t* hbuf = (uint16_t*)(ws + o_hb);
  int*      flags= (int*)(ws + o_fl);

  hipMemsetAsync(ws + o_hb, 0, (size_t)64 * 1024 * 2, stream);           // h_0 = 0
  hipMemsetAsync(ws + o_fl, 0, NWG2 * FLAGSTRIDE * sizeof(int), stream); // flags = 0 every replay

  k0a_cvt<<<2048, 256, 0, stream>>>(embeds, ebf, (512 * 64 * 1024) / 8);
  k0b_trans<<<dim3(32, 64), 256, 0, stream>>>(w, wT);
  k1_xw<<<8192, 256, 0, stream>>>(ebf, wT, bias, xw);

  (void)hipFuncSetAttribute((const void*)k2_rec,
                            hipFuncAttributeMaxDynamicSharedMemorySize, 131072);
  k2_rec<<<NWG2, 256, 131072, stream>>>(xw, wT, hbuf, flags, outp);
}